// Round 7
// baseline (5541.489 us; speedup 1.0000x reference)
//
#include <hip/hip_runtime.h>
#include <cstdint>

typedef __attribute__((ext_vector_type(4))) float f32x4;
typedef __attribute__((ext_vector_type(8))) short s16x8;
typedef __attribute__((ext_vector_type(8))) unsigned short u16x8;
typedef __attribute__((ext_vector_type(4))) unsigned short u16x4;

#define DEVI __device__ __forceinline__

namespace {

constexpr int B = 32, L = 2048, D = 1024, H = 16;
constexpr int CHUNK = 128, MEM = 64, T = 192;
constexpr int NC = 16;

DEVI unsigned short f2bf(float f) {
  unsigned x = __builtin_bit_cast(unsigned, f);
  return (unsigned short)((x + 0x7fffu + ((x >> 16) & 1u)) >> 16);
}

typedef const __attribute__((address_space(1))) unsigned char ga_t;
typedef __attribute__((address_space(3))) unsigned char la_t;

DEVI void gload16(const void* g, void* l) {
  __builtin_amdgcn_global_load_lds((ga_t*)g, (la_t*)l, 16, 0, 0);
}

__global__ void k_cvt(const float* __restrict__ in, unsigned short* __restrict__ out, int n) {
  int i = blockIdx.x * 256 + threadIdx.x;
  if (i < n) out[i] = f2bf(in[i]);
}

__global__ void k_copy_mem(const float* __restrict__ src, float* __restrict__ dst) {
  int i = blockIdx.x * 256 + threadIdx.x;
  dst[i] = src[i];
}

// Wave-per-row LN: 4 rows per 256-thread block, no LDS, pure shuffle reduce.
template<int MODE>
__global__ __launch_bounds__(256) void k_lnw(
    const float* __restrict__ memb, const float* __restrict__ mem_init,
    const float* __restrict__ pos,
    const float* __restrict__ embP, const float* __restrict__ embS,
    const int* __restrict__ ipr, const int* __restrict__ isk,
    const float* __restrict__ gg, const float* __restrict__ bb,
    float* __restrict__ z, unsigned short* __restrict__ lnout, int t)
{
  const int tid = threadIdx.x, lane = tid & 63, wid = tid >> 6;
  const int row = blockIdx.x * 4 + wid;      // 0 .. B*T-1
  const int b = row / T, i = row % T;
  const int c0 = lane * 4;

  float v[16];
  if constexpr (MODE == 0) {
    if (i < MEM) {
      const float* src = (t == 0) ? (mem_init + (size_t)i * D)
                                  : (memb + ((size_t)b * MEM + i) * D);
      #pragma unroll
      for (int k = 0; k < 4; ++k) {
        const int c = k * 256 + c0;
        const f32x4 s = *reinterpret_cast<const f32x4*>(&src[c]);
        const f32x4 p = *reinterpret_cast<const f32x4*>(&pos[i * D + c]);
        #pragma unroll
        for (int e = 0; e < 4; ++e) v[k * 4 + e] = s[e] + p[e];
      }
    } else {
      const int j = t * CHUNK + (i - MEM);
      const int pi = ipr[b * L + j], si = isk[b * L + j];
      #pragma unroll
      for (int k = 0; k < 4; ++k) {
        const int c = k * 256 + c0;
        const f32x4 ep = *reinterpret_cast<const f32x4*>(&embP[(size_t)pi * D + c]);
        const f32x4 es = *reinterpret_cast<const f32x4*>(&embS[(size_t)si * D + c]);
        const f32x4 p  = *reinterpret_cast<const f32x4*>(&pos[i * D + c]);
        #pragma unroll
        for (int e = 0; e < 4; ++e) v[k * 4 + e] = ep[e] + es[e] + p[e];
      }
    }
  } else {
    #pragma unroll
    for (int k = 0; k < 4; ++k) {
      const f32x4 zz = *reinterpret_cast<const f32x4*>(&z[(size_t)row * D + k * 256 + c0]);
      #pragma unroll
      for (int e = 0; e < 4; ++e) v[k * 4 + e] = zz[e];
    }
  }
  float s = 0.f, s2 = 0.f;
  #pragma unroll
  for (int e = 0; e < 16; ++e) { s += v[e]; s2 += v[e] * v[e]; }
  #pragma unroll
  for (int m = 1; m < 64; m <<= 1) { s += __shfl_xor(s, m, 64); s2 += __shfl_xor(s2, m, 64); }
  const float mu  = s * (1.0f / 1024.0f);
  const float var = s2 * (1.0f / 1024.0f) - mu * mu;
  const float rs  = rsqrtf(var + 1e-5f);
  if constexpr (MODE == 0) {
    #pragma unroll
    for (int k = 0; k < 4; ++k) {
      f32x4 zz = {v[k*4+0], v[k*4+1], v[k*4+2], v[k*4+3]};
      *reinterpret_cast<f32x4*>(&z[(size_t)row * D + k * 256 + c0]) = zz;
    }
  }
  #pragma unroll
  for (int k = 0; k < 4; ++k) {
    const int c = k * 256 + c0;
    u16x4 o;
    #pragma unroll
    for (int e = 0; e < 4; ++e)
      o[e] = f2bf((v[k * 4 + e] - mu) * rs * gg[c + e] + bb[c + e]);
    *reinterpret_cast<u16x4*>(&lnout[(size_t)row * D + c]) = o;
  }
}

struct GArgs {
  const unsigned short* A; const unsigned short* W; const float* bias;
  unsigned short* outb; float* z; float* outf; unsigned short* candb; float* mem;
  int M, N, K, t;
};

// ---- 3-buffer pipelined 128x128 GEMM (T3 2-phase + T4 counted vmcnt) ----
// Per K-tile (BK=32): entering iteration t, buf[t%3] is certified.
//   stage(t+2) -> buf[(t+2)%3];  8 ds_read_b128 + 16 MFMA from buf[t%3];
//   s_waitcnt vmcnt(4)  (certifies t+1's 4 loads, leaves t+2's in flight);
//   s_barrier.
// Issue->wait lag = 2 full tiles (~2x compute phase >= L2 latency); vmcnt
// never drains to 0 in steady state. 48 KB LDS -> 3 blocks/CU TLP retained.
// EPI 0: bf16 out   1: relu->bf16   2: z += v
// EPI 3: zv=z+v; i<MEM -> z & cand_bf16 ; else -> d_out
// EPI 4: gate: mem = (t==0) ? cand : sig(v)*cand + (1-sig(v))*mem
template<int EPI>
__global__ __launch_bounds__(256) void k_gemmp(GArgs a)
{
  __shared__ __align__(16) unsigned short Al[3][128 * 32];
  __shared__ __align__(16) unsigned short Bl[3][128 * 32];
  const int tid = threadIdx.x;
  const int lane = tid & 63, wid = tid >> 6;
  const int gx = gridDim.x;
  const int nwg = gx * gridDim.y;
  const int f = blockIdx.y * gx + blockIdx.x;
  const int tile = (f & 7) * (nwg >> 3) + (f >> 3);
  const int brow = (tile / gx) * 128, bcol = (tile % gx) * 128;
  const int wr = wid >> 1, wc = wid & 1;
  const int c0 = lane & 15, g4 = lane >> 4;
  const int K = a.K;

  // staging: position p in [0,512): row p>>2, 16B-octet p&3.
  // thread covers p = tid and p = tid + 256. Dest is linear: byte p*16.
  const int r0 = tid >> 2, oc8 = (tid & 3) * 8;
  const int dst0 = wid * 512, dst1 = 2048 + wid * 512;   // shorts

  f32x4 acc[4][4] = {};

  const unsigned short* __restrict__ Ag = a.A;
  const unsigned short* __restrict__ Wg = a.W;

  auto stage = [&](int t1, int buf) {
    const int kb = t1 * 32;
    gload16(&Ag[(size_t)(brow + r0) * K + kb + oc8],      &Al[buf][dst0]);
    gload16(&Ag[(size_t)(brow + 64 + r0) * K + kb + oc8], &Al[buf][dst1]);
    gload16(&Wg[(size_t)(bcol + r0) * K + kb + oc8],      &Bl[buf][dst0]);
    gload16(&Wg[(size_t)(bcol + 64 + r0) * K + kb + oc8], &Bl[buf][dst1]);
  };

  const int nt = K >> 5;
  // prologue: stage tiles 0,1; certify tile 0 (vmcnt(4) leaves tile 1 in flight)
  stage(0, 0);
  stage(1, 1);
  asm volatile("s_waitcnt vmcnt(4)" ::: "memory");
  __builtin_amdgcn_s_barrier();
  asm volatile("" ::: "memory");

  for (int t = 0; t < nt; ++t) {
    const int cb = t % 3;
    if (t + 2 < nt) stage(t + 2, (t + 2) % 3);
    s16x8 af[4], bf[4];
    #pragma unroll
    for (int m = 0; m < 4; ++m)
      af[m] = *reinterpret_cast<const s16x8*>(&Al[cb][(wr * 64 + m * 16 + c0) * 32 + g4 * 8]);
    #pragma unroll
    for (int n = 0; n < 4; ++n)
      bf[n] = *reinterpret_cast<const s16x8*>(&Bl[cb][(wc * 64 + n * 16 + c0) * 32 + g4 * 8]);
    #pragma unroll
    for (int m = 0; m < 4; ++m)
      #pragma unroll
      for (int n = 0; n < 4; ++n)
        acc[m][n] = __builtin_amdgcn_mfma_f32_16x16x32_bf16(af[m], bf[n], acc[m][n], 0, 0, 0);
    if (t + 1 < nt) {
      if (t + 2 < nt) { asm volatile("s_waitcnt vmcnt(4)" ::: "memory"); }
      else            { asm volatile("s_waitcnt vmcnt(0)" ::: "memory"); }
      __builtin_amdgcn_s_barrier();
      asm volatile("" ::: "memory");
    }
  }

  #pragma unroll
  for (int m = 0; m < 4; ++m) {
    #pragma unroll
    for (int n = 0; n < 4; ++n) {
      const int col = bcol + wc * 64 + n * 16 + c0;
      const float bv = a.bias[col];
      #pragma unroll
      for (int j = 0; j < 4; ++j) {
        const int row = brow + wr * 64 + m * 16 + g4 * 4 + j;
        float v = acc[m][n][j] + bv;
        if constexpr (EPI == 0) {
          a.outb[(size_t)row * a.N + col] = f2bf(v);
        } else if constexpr (EPI == 1) {
          a.outb[(size_t)row * a.N + col] = f2bf(v > 0.f ? v : 0.f);
        } else if constexpr (EPI == 2) {
          a.z[(size_t)row * a.N + col] += v;
        } else if constexpr (EPI == 3) {
          const float zv = a.z[(size_t)row * a.N + col] + v;
          const int bb2 = row / T, ii = row % T;
          if (ii < MEM) {
            a.z[(size_t)row * a.N + col] = zv;
            a.candb[((size_t)bb2 * MEM + ii) * D + col] = f2bf(zv);
          } else {
            a.outf[((size_t)bb2 * L + a.t * CHUNK + (ii - MEM)) * D + col] = zv;
          }
        } else {
          const float g = 1.0f / (1.0f + __expf(-v));
          const int bb2 = row >> 6, ii = row & 63;
          const float cand = a.z[((size_t)bb2 * T + ii) * D + col];
          const float mo = a.mem[(size_t)row * D + col];
          a.mem[(size_t)row * D + col] = (a.t == 0) ? cand : g * cand + (1.0f - g) * mo;
        }
      }
    }
  }
}

// One workgroup per (b,h). qkv: [B*T][3072] bf16 (q|k|v each H*64 cols).
__global__ __launch_bounds__(256) void k_attn(const unsigned short* __restrict__ qkv,
                                              unsigned short* __restrict__ attno)
{
  __shared__ unsigned short Ks[192 * 64];
  __shared__ unsigned short Vt[64 * 192];
  __shared__ unsigned short Pl[4][16 * 200];
  const int tid = threadIdx.x, lane = tid & 63, wid = tid >> 6;
  const int b = blockIdx.x >> 4, h = blockIdx.x & 15;
  const size_t base = (size_t)b * T * 3072 + h * 64;

  #pragma unroll
  for (int it = 0; it < 6; ++it) {
    const int cidx = tid + it * 256;
    const int key = cidx >> 3, hb = cidx & 7;
    const u16x8 kv = *reinterpret_cast<const u16x8*>(&qkv[base + (size_t)key * 3072 + 1024 + hb * 8]);
    *reinterpret_cast<u16x8*>(&Ks[key * 64 + ((hb ^ (key & 7)) * 8)]) = kv;
    const u16x8 vv = *reinterpret_cast<const u16x8*>(&qkv[base + (size_t)key * 3072 + 2048 + hb * 8]);
    #pragma unroll
    for (int e = 0; e < 8; ++e) {
      const int hd = hb * 8 + e;
      Vt[hd * 192 + (((key >> 3) + hd) % 24) * 8 + (key & 7)] = vv[e];
    }
  }
  __syncthreads();

  const int c0 = lane & 15, g4 = lane >> 4;
  for (int qb = wid; qb < 12; qb += 4) {
    s16x8 qf[2];
    #pragma unroll
    for (int kk = 0; kk < 2; ++kk)
      qf[kk] = *reinterpret_cast<const s16x8*>(&qkv[base + (size_t)(qb * 16 + c0) * 3072 + kk * 32 + g4 * 8]);
    f32x4 sc[12];
    #pragma unroll
    for (int cb = 0; cb < 12; ++cb) {
      f32x4 s4 = {};
      #pragma unroll
      for (int kk = 0; kk < 2; ++kk) {
        const s16x8 kf = *reinterpret_cast<const s16x8*>(
            &Ks[(cb * 16 + c0) * 64 + (((kk * 4 + g4) ^ (c0 & 7)) * 8)]);
        s4 = __builtin_amdgcn_mfma_f32_16x16x32_bf16(qf[kk], kf, s4, 0, 0, 0);
      }
      sc[cb] = s4;
    }
    #pragma unroll
    for (int j = 0; j < 4; ++j) {
      const int qi = qb * 16 + g4 * 4 + j;
      float mj = -1e30f;
      #pragma unroll
      for (int cb = 0; cb < 12; ++cb) {
        const int kj = cb * 16 + c0;
        float sv = sc[cb][j] * 0.125f;
        if (qi >= MEM && kj > qi) sv = -1e30f;
        sc[cb][j] = sv;
        mj = fmaxf(mj, sv);
      }
      #pragma unroll
      for (int msk = 1; msk <= 8; msk <<= 1) mj = fmaxf(mj, __shfl_xor(mj, msk, 64));
      float sum = 0.f;
      #pragma unroll
      for (int cb = 0; cb < 12; ++cb) {
        const float p = exp2f((sc[cb][j] - mj) * 1.44269504f);
        sc[cb][j] = p;
        sum += p;
      }
      #pragma unroll
      for (int msk = 1; msk <= 8; msk <<= 1) sum += __shfl_xor(sum, msk, 64);
      const float rin = 1.0f / sum;
      #pragma unroll
      for (int cb = 0; cb < 12; ++cb)
        Pl[wid][(g4 * 4 + j) * 200 + cb * 16 + c0] = f2bf(sc[cb][j] * rin);
    }
    #pragma unroll
    for (int cb2 = 0; cb2 < 4; ++cb2) {
      f32x4 ao = {};
      const int hd = cb2 * 16 + c0;
      #pragma unroll
      for (int kk = 0; kk < 6; ++kk) {
        const int k0 = kk * 32 + g4 * 8;
        const s16x8 pf = *reinterpret_cast<const s16x8*>(&Pl[wid][c0 * 200 + k0]);
        const s16x8 vf = *reinterpret_cast<const s16x8*>(&Vt[hd * 192 + (((k0 >> 3) + hd) % 24) * 8]);
        ao = __builtin_amdgcn_mfma_f32_16x16x32_bf16(pf, vf, ao, 0, 0, 0);
      }
      #pragma unroll
      for (int j = 0; j < 4; ++j) {
        const int q = qb * 16 + g4 * 4 + j;
        attno[((size_t)b * T + q) * D + h * 64 + cb2 * 16 + c0] = f2bf(ao[j]);
      }
    }
  }
}

} // namespace

extern "C" void kernel_launch(void* const* d_in, const int* in_sizes, int n_in,
                              void* d_out, int out_size, void* d_ws, size_t ws_size,
                              hipStream_t stream)
{
  const int*   ipr      = (const int*)d_in[0];
  const int*   isk      = (const int*)d_in[1];
  const float* embP     = (const float*)d_in[2];
  const float* embS     = (const float*)d_in[3];
  const float* mem_init = (const float*)d_in[4];
  const float* pos      = (const float*)d_in[5];
  const float* wqkv     = (const float*)d_in[6];
  const float* bqkv     = (const float*)d_in[7];
  const float* wo       = (const float*)d_in[8];
  const float* bo       = (const float*)d_in[9];
  const float* w1       = (const float*)d_in[10];
  const float* b1       = (const float*)d_in[11];
  const float* w2       = (const float*)d_in[12];
  const float* b2       = (const float*)d_in[13];
  const float* ln_a_g   = (const float*)d_in[14];
  const float* ln_a_b   = (const float*)d_in[15];
  const float* ln_f_g   = (const float*)d_in[16];
  const float* ln_f_b   = (const float*)d_in[17];
  const float* gw       = (const float*)d_in[18];
  const float* gb       = (const float*)d_in[19];
  float* out = (float*)d_out;
  (void)in_sizes; (void)n_in; (void)out_size; (void)ws_size;

  char* ws = (char*)d_ws;
  size_t off = 0;
  auto alloc = [&](size_t bytes) -> void* {
    void* p = ws + off; off += (bytes + 255) & ~(size_t)255; return p;
  };
  unsigned short* wqkv_b = (unsigned short*)alloc((size_t)3072 * 1024 * 2);
  unsigned short* wo_b   = (unsigned short*)alloc((size_t)1024 * 1024 * 2);
  unsigned short* w1_b   = (unsigned short*)alloc((size_t)4096 * 1024 * 2);
  unsigned short* w2_b   = (unsigned short*)alloc((size_t)1024 * 4096 * 2);
  unsigned short* gw_b   = (unsigned short*)alloc((size_t)1024 * 1024 * 2);
  float*          z      = (float*)alloc((size_t)B * T * D * 4);
  unsigned short* lnb    = (unsigned short*)alloc((size_t)B * T * D * 2);
  unsigned short* atno   = (unsigned short*)alloc((size_t)B * T * D * 2);
  unsigned short* big    = (unsigned short*)alloc((size_t)B * T * 4096 * 2); // qkv then ffn1
  unsigned short* candb  = (unsigned short*)alloc((size_t)B * MEM * D * 2);
  float*          memb   = (float*)alloc((size_t)B * MEM * D * 4);

  k_cvt<<<(3072 * 1024) / 256, 256, 0, stream>>>(wqkv, wqkv_b, 3072 * 1024);
  k_cvt<<<(1024 * 1024) / 256, 256, 0, stream>>>(wo,   wo_b,   1024 * 1024);
  k_cvt<<<(4096 * 1024) / 256, 256, 0, stream>>>(w1,   w1_b,   4096 * 1024);
  k_cvt<<<(1024 * 4096) / 256, 256, 0, stream>>>(w2,   w2_b,   1024 * 4096);
  k_cvt<<<(1024 * 1024) / 256, 256, 0, stream>>>(gw,   gw_b,   1024 * 1024);

  for (int t = 0; t < NC; ++t) {
    k_lnw<0><<<(B * T) / 4, 256, 0, stream>>>(memb, mem_init, pos, embP, embS, ipr, isk,
                                              ln_a_g, ln_a_b, z, lnb, t);
    { GArgs a{lnb, wqkv_b, bqkv, big, nullptr, nullptr, nullptr, nullptr, B * T, 3072, 1024, t};
      k_gemmp<0><<<dim3(3072 / 128, (B * T) / 128), 256, 0, stream>>>(a); }
    k_attn<<<B * H, 256, 0, stream>>>(big, atno);
    { GArgs a{atno, wo_b, bo, nullptr, z, nullptr, nullptr, nullptr, B * T, 1024, 1024, t};
      k_gemmp<2><<<dim3(1024 / 128, (B * T) / 128), 256, 0, stream>>>(a); }
    k_lnw<1><<<(B * T) / 4, 256, 0, stream>>>(nullptr, nullptr, nullptr, nullptr, nullptr,
                                              nullptr, nullptr, ln_f_g, ln_f_b, z, lnb, t);
    { GArgs a{lnb, w1_b, b1, big, nullptr, nullptr, nullptr, nullptr, B * T, 4096, 1024, t};
      k_gemmp<1><<<dim3(4096 / 128, (B * T) / 128), 256, 0, stream>>>(a); }
    { GArgs a{big, w2_b, b2, nullptr, z, out, candb, nullptr, B * T, 1024, 4096, t};
      k_gemmp<3><<<dim3(1024 / 128, (B * T) / 128), 256, 0, stream>>>(a); }
    { GArgs a{candb, gw_b, gb, nullptr, z, nullptr, nullptr, memb, B * MEM, 1024, 1024, t};
      k_gemmp<4><<<dim3(1024 / 128, (B * MEM) / 128), 256, 0, stream>>>(a); }
  }
  k_copy_mem<<<(B * MEM * D) / 256, 256, 0, stream>>>(memb, out + (size_t)B * L * D);
}

// Round 8
// 4878.936 us; speedup vs baseline: 1.1358x; 1.1358x over previous
//
#include <hip/hip_runtime.h>
#include <cstdint>

typedef __attribute__((ext_vector_type(4))) float f32x4;
typedef __attribute__((ext_vector_type(8))) short s16x8;
typedef __attribute__((ext_vector_type(8))) unsigned short u16x8;
typedef __attribute__((ext_vector_type(4))) unsigned short u16x4;

#define DEVI __device__ __forceinline__

namespace {

constexpr int B = 32, L = 2048, D = 1024, H = 16;
constexpr int CHUNK = 128, MEM = 64, T = 192;
constexpr int NC = 16;

DEVI unsigned short f2bf(float f) {
  unsigned x = __builtin_bit_cast(unsigned, f);
  return (unsigned short)((x + 0x7fffu + ((x >> 16) & 1u)) >> 16);
}

typedef const __attribute__((address_space(1))) unsigned char ga_t;
typedef __attribute__((address_space(3))) unsigned char la_t;

DEVI void gload16(const void* g, void* l) {
  __builtin_amdgcn_global_load_lds((ga_t*)g, (la_t*)l, 16, 0, 0);
}

__global__ void k_cvt(const float* __restrict__ in, unsigned short* __restrict__ out, int n) {
  int i = blockIdx.x * 256 + threadIdx.x;
  if (i < n) out[i] = f2bf(in[i]);
}

__global__ void k_copy_mem(const float* __restrict__ src, float* __restrict__ dst) {
  int i = blockIdx.x * 256 + threadIdx.x;
  dst[i] = src[i];
}

// Wave-per-row LN: 4 rows per 256-thread block, no LDS, pure shuffle reduce.
template<int MODE>
__global__ __launch_bounds__(256) void k_lnw(
    const float* __restrict__ memb, const float* __restrict__ mem_init,
    const float* __restrict__ pos,
    const float* __restrict__ embP, const float* __restrict__ embS,
    const int* __restrict__ ipr, const int* __restrict__ isk,
    const float* __restrict__ gg, const float* __restrict__ bb,
    float* __restrict__ z, unsigned short* __restrict__ lnout, int t)
{
  const int tid = threadIdx.x, lane = tid & 63, wid = tid >> 6;
  const int row = blockIdx.x * 4 + wid;      // 0 .. B*T-1
  const int b = row / T, i = row % T;
  const int c0 = lane * 4;

  float v[16];
  if constexpr (MODE == 0) {
    if (i < MEM) {
      const float* src = (t == 0) ? (mem_init + (size_t)i * D)
                                  : (memb + ((size_t)b * MEM + i) * D);
      #pragma unroll
      for (int k = 0; k < 4; ++k) {
        const int c = k * 256 + c0;
        const f32x4 s = *reinterpret_cast<const f32x4*>(&src[c]);
        const f32x4 p = *reinterpret_cast<const f32x4*>(&pos[i * D + c]);
        #pragma unroll
        for (int e = 0; e < 4; ++e) v[k * 4 + e] = s[e] + p[e];
      }
    } else {
      const int j = t * CHUNK + (i - MEM);
      const int pi = ipr[b * L + j], si = isk[b * L + j];
      #pragma unroll
      for (int k = 0; k < 4; ++k) {
        const int c = k * 256 + c0;
        const f32x4 ep = *reinterpret_cast<const f32x4*>(&embP[(size_t)pi * D + c]);
        const f32x4 es = *reinterpret_cast<const f32x4*>(&embS[(size_t)si * D + c]);
        const f32x4 p  = *reinterpret_cast<const f32x4*>(&pos[i * D + c]);
        #pragma unroll
        for (int e = 0; e < 4; ++e) v[k * 4 + e] = ep[e] + es[e] + p[e];
      }
    }
  } else {
    #pragma unroll
    for (int k = 0; k < 4; ++k) {
      const f32x4 zz = *reinterpret_cast<const f32x4*>(&z[(size_t)row * D + k * 256 + c0]);
      #pragma unroll
      for (int e = 0; e < 4; ++e) v[k * 4 + e] = zz[e];
    }
  }
  float s = 0.f, s2 = 0.f;
  #pragma unroll
  for (int e = 0; e < 16; ++e) { s += v[e]; s2 += v[e] * v[e]; }
  #pragma unroll
  for (int m = 1; m < 64; m <<= 1) { s += __shfl_xor(s, m, 64); s2 += __shfl_xor(s2, m, 64); }
  const float mu  = s * (1.0f / 1024.0f);
  const float var = s2 * (1.0f / 1024.0f) - mu * mu;
  const float rs  = rsqrtf(var + 1e-5f);
  if constexpr (MODE == 0) {
    #pragma unroll
    for (int k = 0; k < 4; ++k) {
      f32x4 zz = {v[k*4+0], v[k*4+1], v[k*4+2], v[k*4+3]};
      *reinterpret_cast<f32x4*>(&z[(size_t)row * D + k * 256 + c0]) = zz;
    }
  }
  #pragma unroll
  for (int k = 0; k < 4; ++k) {
    const int c = k * 256 + c0;
    u16x4 o;
    #pragma unroll
    for (int e = 0; e < 4; ++e)
      o[e] = f2bf((v[k * 4 + e] - mu) * rs * gg[c + e] + bb[c + e]);
    *reinterpret_cast<u16x4*>(&lnout[(size_t)row * D + c]) = o;
  }
}

struct GArgs {
  const unsigned short* A; const unsigned short* W; const float* bias;
  unsigned short* outb; float* z; float* outf; unsigned short* candb; float* mem;
  int M, N, K, t;
};

// ---- 2-phase double-buffered 128x128 GEMM (round-6 proven structure) ----
// Per K-slice tile (BK=32): { barrier (drains vmcnt -> buf[cur] certified);
//   stage(t+1) -> buf[cur^1]; 8 ds_read_b128 + 16 MFMA from buf[cur] }.
// SPLITK: gridDim.z slices of K; EPI 8 stores f32 partials (no bias).
// EPI 0: bf16 out   1: relu->bf16   2: z += v   8: partial f32 store
template<int EPI, int SPLITK>
__global__ __launch_bounds__(256) void k_gemmp(GArgs a)
{
  __shared__ __align__(16) unsigned short Al[2][128 * 32];
  __shared__ __align__(16) unsigned short Bl[2][128 * 32];
  const int tid = threadIdx.x;
  const int lane = tid & 63, wid = tid >> 6;
  const int gx = gridDim.x;
  const int nwg = gx * gridDim.y;
  const int f = blockIdx.y * gx + blockIdx.x;
  const int tile = (f & 7) * (nwg >> 3) + (f >> 3);
  const int brow = (tile / gx) * 128, bcol = (tile % gx) * 128;
  const int wr = wid >> 1, wc = wid & 1;
  const int c0 = lane & 15, g4 = lane >> 4;
  const int K = a.K;
  const int Ks = K / SPLITK;
  const int kbase = blockIdx.z * Ks;

  const int r0 = tid >> 2, oc8 = (tid & 3) * 8;
  const int dst0 = wid * 512, dst1 = 2048 + wid * 512;   // shorts

  f32x4 acc[4][4] = {};

  const unsigned short* __restrict__ Ag = a.A;
  const unsigned short* __restrict__ Wg = a.W;

  auto stage = [&](int t1, int buf) {
    const int kb = kbase + t1 * 32;
    gload16(&Ag[(size_t)(brow + r0) * K + kb + oc8],      &Al[buf][dst0]);
    gload16(&Ag[(size_t)(brow + 64 + r0) * K + kb + oc8], &Al[buf][dst1]);
    gload16(&Wg[(size_t)(bcol + r0) * K + kb + oc8],      &Bl[buf][dst0]);
    gload16(&Wg[(size_t)(bcol + 64 + r0) * K + kb + oc8], &Bl[buf][dst1]);
  };

  stage(0, 0);
  const int nt = Ks >> 5;
  int cur = 0;
  for (int t = 0; t < nt; ++t) {
    __syncthreads();                    // drains vmcnt: buf[cur] ready; buf[cur^1] free
    if (t + 1 < nt) stage(t + 1, cur ^ 1);
    s16x8 af[4], bf[4];
    #pragma unroll
    for (int m = 0; m < 4; ++m)
      af[m] = *reinterpret_cast<const s16x8*>(&Al[cur][(wr * 64 + m * 16 + c0) * 32 + g4 * 8]);
    #pragma unroll
    for (int n = 0; n < 4; ++n)
      bf[n] = *reinterpret_cast<const s16x8*>(&Bl[cur][(wc * 64 + n * 16 + c0) * 32 + g4 * 8]);
    #pragma unroll
    for (int m = 0; m < 4; ++m)
      #pragma unroll
      for (int n = 0; n < 4; ++n)
        acc[m][n] = __builtin_amdgcn_mfma_f32_16x16x32_bf16(af[m], bf[n], acc[m][n], 0, 0, 0);
    cur ^= 1;
  }

  #pragma unroll
  for (int m = 0; m < 4; ++m) {
    #pragma unroll
    for (int n = 0; n < 4; ++n) {
      const int col = bcol + wc * 64 + n * 16 + c0;
      float bv = 0.f;
      if constexpr (EPI != 8) bv = a.bias[col];
      #pragma unroll
      for (int j = 0; j < 4; ++j) {
        const int row = brow + wr * 64 + m * 16 + g4 * 4 + j;
        float v = acc[m][n][j] + bv;
        if constexpr (EPI == 0) {
          a.outb[(size_t)row * a.N + col] = f2bf(v);
        } else if constexpr (EPI == 1) {
          a.outb[(size_t)row * a.N + col] = f2bf(v > 0.f ? v : 0.f);
        } else if constexpr (EPI == 2) {
          a.z[(size_t)row * a.N + col] += v;
        } else if constexpr (EPI == 8) {
          a.outf[(size_t)blockIdx.z * a.M * a.N + (size_t)row * a.N + col] = v;
        }
      }
    }
  }
}

// FFN2 reduce: one row per block. v = p0+p1+bias; zv = z+v;
// mem rows -> z & candb(bf16); chunk rows -> d_out.
__global__ __launch_bounds__(256) void k_red2(
    const float* __restrict__ p, float* __restrict__ z, const float* __restrict__ bias,
    float* __restrict__ out, unsigned short* __restrict__ candb, int t)
{
  const int row = blockIdx.x;            // 0 .. B*T-1
  const int b = row / T, i = row % T;
  const int c = threadIdx.x * 4;
  const size_t MN = (size_t)B * T * D;
  const f32x4 p0 = *reinterpret_cast<const f32x4*>(&p[(size_t)row * D + c]);
  const f32x4 p1 = *reinterpret_cast<const f32x4*>(&p[MN + (size_t)row * D + c]);
  const f32x4 bb = *reinterpret_cast<const f32x4*>(&bias[c]);
  const f32x4 zz = *reinterpret_cast<const f32x4*>(&z[(size_t)row * D + c]);
  f32x4 zv;
  #pragma unroll
  for (int e = 0; e < 4; ++e) zv[e] = zz[e] + p0[e] + p1[e] + bb[e];
  if (i < MEM) {
    *reinterpret_cast<f32x4*>(&z[(size_t)row * D + c]) = zv;
    u16x4 o;
    #pragma unroll
    for (int e = 0; e < 4; ++e) o[e] = f2bf(zv[e]);
    *reinterpret_cast<u16x4*>(&candb[((size_t)b * MEM + i) * D + c]) = o;
  } else {
    *reinterpret_cast<f32x4*>(&out[((size_t)b * L + t * CHUNK + (i - MEM)) * D + c]) = zv;
  }
}

// Gate reduce: one row per block (B*MEM rows). s = sum p[0..3] + gb;
// mem = (t==0) ? cand : sig(s)*cand + (1-sig(s))*mem.
__global__ __launch_bounds__(256) void k_redg(
    const float* __restrict__ p, const float* __restrict__ z,
    const float* __restrict__ gb, float* __restrict__ memb, int t)
{
  const int row = blockIdx.x;            // 0 .. B*MEM-1
  const int b = row >> 6, i = row & 63;
  const int c = threadIdx.x * 4;
  const size_t MN = (size_t)B * MEM * D;
  f32x4 s = *reinterpret_cast<const f32x4*>(&gb[c]);
  #pragma unroll
  for (int k = 0; k < 4; ++k) {
    const f32x4 pk = *reinterpret_cast<const f32x4*>(&p[k * MN + (size_t)row * D + c]);
    #pragma unroll
    for (int e = 0; e < 4; ++e) s[e] += pk[e];
  }
  const f32x4 cand = *reinterpret_cast<const f32x4*>(&z[((size_t)b * T + i) * D + c]);
  f32x4 mo = *reinterpret_cast<f32x4*>(&memb[(size_t)row * D + c]);
  f32x4 r;
  #pragma unroll
  for (int e = 0; e < 4; ++e) {
    const float g = 1.0f / (1.0f + __expf(-s[e]));
    r[e] = (t == 0) ? cand[e] : g * cand[e] + (1.0f - g) * mo[e];
  }
  *reinterpret_cast<f32x4*>(&memb[(size_t)row * D + c]) = r;
}

// One workgroup per (b,h). qkv: [B*T][3072] bf16 (q|k|v each H*64 cols).
__global__ __launch_bounds__(256) void k_attn(const unsigned short* __restrict__ qkv,
                                              unsigned short* __restrict__ attno)
{
  __shared__ unsigned short Ks[192 * 64];
  __shared__ unsigned short Vt[64 * 192];
  __shared__ unsigned short Pl[4][16 * 200];
  const int tid = threadIdx.x, lane = tid & 63, wid = tid >> 6;
  const int b = blockIdx.x >> 4, h = blockIdx.x & 15;
  const size_t base = (size_t)b * T * 3072 + h * 64;

  #pragma unroll
  for (int it = 0; it < 6; ++it) {
    const int cidx = tid + it * 256;
    const int key = cidx >> 3, hb = cidx & 7;
    const u16x8 kv = *reinterpret_cast<const u16x8*>(&qkv[base + (size_t)key * 3072 + 1024 + hb * 8]);
    *reinterpret_cast<u16x8*>(&Ks[key * 64 + ((hb ^ (key & 7)) * 8)]) = kv;
    const u16x8 vv = *reinterpret_cast<const u16x8*>(&qkv[base + (size_t)key * 3072 + 2048 + hb * 8]);
    #pragma unroll
    for (int e = 0; e < 8; ++e) {
      const int hd = hb * 8 + e;
      Vt[hd * 192 + (((key >> 3) + hd) % 24) * 8 + (key & 7)] = vv[e];
    }
  }
  __syncthreads();

  const int c0 = lane & 15, g4 = lane >> 4;
  for (int qb = wid; qb < 12; qb += 4) {
    s16x8 qf[2];
    #pragma unroll
    for (int kk = 0; kk < 2; ++kk)
      qf[kk] = *reinterpret_cast<const s16x8*>(&qkv[base + (size_t)(qb * 16 + c0) * 3072 + kk * 32 + g4 * 8]);
    f32x4 sc[12];
    #pragma unroll
    for (int cb = 0; cb < 12; ++cb) {
      f32x4 s4 = {};
      #pragma unroll
      for (int kk = 0; kk < 2; ++kk) {
        const s16x8 kf = *reinterpret_cast<const s16x8*>(
            &Ks[(cb * 16 + c0) * 64 + (((kk * 4 + g4) ^ (c0 & 7)) * 8)]);
        s4 = __builtin_amdgcn_mfma_f32_16x16x32_bf16(qf[kk], kf, s4, 0, 0, 0);
      }
      sc[cb] = s4;
    }
    #pragma unroll
    for (int j = 0; j < 4; ++j) {
      const int qi = qb * 16 + g4 * 4 + j;
      float mj = -1e30f;
      #pragma unroll
      for (int cb = 0; cb < 12; ++cb) {
        const int kj = cb * 16 + c0;
        float sv = sc[cb][j] * 0.125f;
        if (qi >= MEM && kj > qi) sv = -1e30f;
        sc[cb][j] = sv;
        mj = fmaxf(mj, sv);
      }
      #pragma unroll
      for (int msk = 1; msk <= 8; msk <<= 1) mj = fmaxf(mj, __shfl_xor(mj, msk, 64));
      float sum = 0.f;
      #pragma unroll
      for (int cb = 0; cb < 12; ++cb) {
        const float p = exp2f((sc[cb][j] - mj) * 1.44269504f);
        sc[cb][j] = p;
        sum += p;
      }
      #pragma unroll
      for (int msk = 1; msk <= 8; msk <<= 1) sum += __shfl_xor(sum, msk, 64);
      const float rin = 1.0f / sum;
      #pragma unroll
      for (int cb = 0; cb < 12; ++cb)
        Pl[wid][(g4 * 4 + j) * 200 + cb * 16 + c0] = f2bf(sc[cb][j] * rin);
    }
    #pragma unroll
    for (int cb2 = 0; cb2 < 4; ++cb2) {
      f32x4 ao = {};
      const int hd = cb2 * 16 + c0;
      #pragma unroll
      for (int kk = 0; kk < 6; ++kk) {
        const int k0 = kk * 32 + g4 * 8;
        const s16x8 pf = *reinterpret_cast<const s16x8*>(&Pl[wid][c0 * 200 + k0]);
        const s16x8 vf = *reinterpret_cast<const s16x8*>(&Vt[hd * 192 + (((k0 >> 3) + hd) % 24) * 8]);
        ao = __builtin_amdgcn_mfma_f32_16x16x32_bf16(pf, vf, ao, 0, 0, 0);
      }
      #pragma unroll
      for (int j = 0; j < 4; ++j) {
        const int q = qb * 16 + g4 * 4 + j;
        attno[((size_t)b * T + q) * D + h * 64 + cb2 * 16 + c0] = f2bf(ao[j]);
      }
    }
  }
}

} // namespace

extern "C" void kernel_launch(void* const* d_in, const int* in_sizes, int n_in,
                              void* d_out, int out_size, void* d_ws, size_t ws_size,
                              hipStream_t stream)
{
  const int*   ipr      = (const int*)d_in[0];
  const int*   isk      = (const int*)d_in[1];
  const float* embP     = (const float*)d_in[2];
  const float* embS     = (const float*)d_in[3];
  const float* mem_init = (const float*)d_in[4];
  const float* pos      = (const float*)d_in[5];
  const float* wqkv     = (const float*)d_in[6];
  const float* bqkv     = (const float*)d_in[7];
  const float* wo       = (const float*)d_in[8];
  const float* bo       = (const float*)d_in[9];
  const float* w1       = (const float*)d_in[10];
  const float* b1       = (const float*)d_in[11];
  const float* w2       = (const float*)d_in[12];
  const float* b2       = (const float*)d_in[13];
  const float* ln_a_g   = (const float*)d_in[14];
  const float* ln_a_b   = (const float*)d_in[15];
  const float* ln_f_g   = (const float*)d_in[16];
  const float* ln_f_b   = (const float*)d_in[17];
  const float* gw       = (const float*)d_in[18];
  const float* gb       = (const float*)d_in[19];
  float* out = (float*)d_out;
  (void)in_sizes; (void)n_in; (void)out_size; (void)ws_size;

  char* ws = (char*)d_ws;
  size_t off = 0;
  auto alloc = [&](size_t bytes) -> void* {
    void* p = ws + off; off += (bytes + 255) & ~(size_t)255; return p;
  };
  unsigned short* wqkv_b = (unsigned short*)alloc((size_t)3072 * 1024 * 2);
  unsigned short* wo_b   = (unsigned short*)alloc((size_t)1024 * 1024 * 2);
  unsigned short* w1_b   = (unsigned short*)alloc((size_t)4096 * 1024 * 2);
  unsigned short* w2_b   = (unsigned short*)alloc((size_t)1024 * 4096 * 2);
  unsigned short* gw_b   = (unsigned short*)alloc((size_t)1024 * 1024 * 2);
  float*          z      = (float*)alloc((size_t)B * T * D * 4);
  unsigned short* lnb    = (unsigned short*)alloc((size_t)B * T * D * 2);
  unsigned short* atno   = (unsigned short*)alloc((size_t)B * T * D * 2);
  unsigned short* big    = (unsigned short*)alloc((size_t)B * T * 4096 * 2); // qkv then ffn1
  unsigned short* candb  = (unsigned short*)alloc((size_t)B * MEM * D * 2);
  float*          memb   = (float*)alloc((size_t)B * MEM * D * 4);
  float*          p2     = (float*)alloc((size_t)2 * B * T * D * 4);    // FFN2 partials
  float*          p4     = (float*)alloc((size_t)4 * B * MEM * D * 4);  // gate partials

  k_cvt<<<(3072 * 1024) / 256, 256, 0, stream>>>(wqkv, wqkv_b, 3072 * 1024);
  k_cvt<<<(1024 * 1024) / 256, 256, 0, stream>>>(wo,   wo_b,   1024 * 1024);
  k_cvt<<<(4096 * 1024) / 256, 256, 0, stream>>>(w1,   w1_b,   4096 * 1024);
  k_cvt<<<(1024 * 4096) / 256, 256, 0, stream>>>(w2,   w2_b,   1024 * 4096);
  k_cvt<<<(1024 * 1024) / 256, 256, 0, stream>>>(gw,   gw_b,   1024 * 1024);

  for (int t = 0; t < NC; ++t) {
    k_lnw<0><<<(B * T) / 4, 256, 0, stream>>>(memb, mem_init, pos, embP, embS, ipr, isk,
                                              ln_a_g, ln_a_b, z, lnb, t);
    { GArgs a{lnb, wqkv_b, bqkv, big, nullptr, nullptr, nullptr, nullptr, B * T, 3072, 1024, t};
      k_gemmp<0, 1><<<dim3(3072 / 128, (B * T) / 128), 256, 0, stream>>>(a); }
    k_attn<<<B * H, 256, 0, stream>>>(big, atno);
    { GArgs a{atno, wo_b, bo, nullptr, z, nullptr, nullptr, nullptr, B * T, 1024, 1024, t};
      k_gemmp<2, 1><<<dim3(1024 / 128, (B * T) / 128), 256, 0, stream>>>(a); }
    k_lnw<1><<<(B * T) / 4, 256, 0, stream>>>(nullptr, nullptr, nullptr, nullptr, nullptr,
                                              nullptr, nullptr, ln_f_g, ln_f_b, z, lnb, t);
    { GArgs a{lnb, w1_b, b1, big, nullptr, nullptr, nullptr, nullptr, B * T, 4096, 1024, t};
      k_gemmp<1, 1><<<dim3(4096 / 128, (B * T) / 128), 256, 0, stream>>>(a); }
    // FFN2: split-K=2 partials + fused reduce/epilogue
    { GArgs a{big, w2_b, nullptr, nullptr, nullptr, p2, nullptr, nullptr, B * T, 1024, 4096, t};
      k_gemmp<8, 2><<<dim3(1024 / 128, (B * T) / 128, 2), 256, 0, stream>>>(a); }
    k_red2<<<B * T, 256, 0, stream>>>(p2, z, b2, out, candb, t);
    // gate: split-K=4 partials + fused sigmoid-gate reduce
    { GArgs a{candb, gw_b, nullptr, nullptr, nullptr, p4, nullptr, nullptr, B * MEM, 1024, 1024, t};
      k_gemmp<8, 4><<<dim3(1024 / 128, (B * MEM) / 128, 4), 256, 0, stream>>>(a); }
    k_redg<<<B * MEM, 256, 0, stream>>>(p4, z, gb, memb, t);
  }
  k_copy_mem<<<(B * MEM * D) / 256, 256, 0, stream>>>(memb, out + (size_t)B * L * D);
}